// Round 6
// baseline (458.935 us; speedup 1.0000x reference)
//
#include <hip/hip_runtime.h>

#define NN 100000
#define NE 1600000
#define HID 64
#define TXT 384
#define BATCH 1024
#define NBUCK 391        // ceil(NN/256)
#define SBLK 256         // scatter/hist blocks
#define EPB ((NE + SBLK - 1) / SBLK)   // edges per block = 6250
#define LDK2 72          // layer bf16 stride (144 B)
#define EB2 782          // ceil(NN/128) MFMA row-blocks

typedef __attribute__((ext_vector_type(8))) short short8;
typedef __attribute__((ext_vector_type(4))) float float4v;

__device__ __forceinline__ ushort f2bf(float f) {
  unsigned u = __float_as_uint(f);
  unsigned r = (u + 0x7fffu + ((u >> 16) & 1u)) >> 16;  // round-to-nearest-even
  return (ushort)r;
}
__device__ __forceinline__ float bf2f(ushort u) {
  return __uint_as_float(((unsigned)u) << 16);
}
__device__ __forceinline__ short8 pack8(float4 a, float4 b) {
  short8 s;
  s[0] = (short)f2bf(a.x); s[1] = (short)f2bf(a.y);
  s[2] = (short)f2bf(a.z); s[3] = (short)f2bf(a.w);
  s[4] = (short)f2bf(b.x); s[5] = (short)f2bf(b.y);
  s[6] = (short)f2bf(b.z); s[7] = (short)f2bf(b.w);
  return s;
}

// inclusive block scan: 64-lane shuffle scan + cross-wave combine (2 barriers)
__device__ __forceinline__ int scan_incl(int v, int* lds8) {
  const int lane = threadIdx.x & 63, wv = threadIdx.x >> 6;
  const int nw = blockDim.x >> 6;
  #pragma unroll
  for (int d = 1; d < 64; d <<= 1) {
    int t = __shfl_up(v, d);
    if (lane >= d) v += t;
  }
  if (lane == 63) lds8[wv] = v;
  __syncthreads();
  int add = 0;
  for (int i = 0; i < nw - 1; ++i)
    if (i < wv) add += lds8[i];
  __syncthreads();             // lds8 reusable after return
  return v + add;
}

// ---- init: W pre-tile (blocks 0..11) + bitmap clear (blocks 12..109) --------
__global__ void k_init(const float* __restrict__ W, ushort* __restrict__ Wt,
                       unsigned char* __restrict__ idmap,
                       unsigned char* __restrict__ flag, int* __restrict__ nf) {
  const int b = blockIdx.x, t = threadIdx.x;
  if (b < 12) {
    const int unit = b * 4 + (t >> 6);   // 48 wtile units: ch = unit>>2, nt = unit&3
    const int lane = t & 63;
    const int ch = unit >> 2, nt = unit & 3;
    const int quad = lane >> 4, lr = lane & 15;
    short8 s;
    #pragma unroll
    for (int j = 0; j < 8; ++j)
      s[j] = (short)f2bf(W[(ch * 32 + quad * 8 + j) * 64 + nt * 16 + lr]);
    *(short8*)&Wt[((size_t)unit * 64 + lane) * 8] = s;
  } else {
    const int i = (b - 12) * 256 + t;
    if (i < NN / 4) { ((int*)idmap)[i] = 0; ((int*)flag)[i] = 0; }
    if (i == 0) *nf = 0;
  }
}

// ---- seed ids into idmap + flag (1 block, 1024 threads) ---------------------
__global__ void k_seed(const int* __restrict__ ids,
                       unsigned char* __restrict__ idmap,
                       unsigned char* __restrict__ flag) {
  const int b = threadIdx.x;
  if (b < BATCH) { const int r = ids[b]; idmap[r] = 1; flag[r] = 1; }
}

// ---- one edge pass marks 1-hop frontier (both directions) -------------------
__global__ void k_fedges(const int* __restrict__ src, const int* __restrict__ dst,
                         const unsigned char* __restrict__ idmap,
                         unsigned char* __restrict__ flag) {
  const int t = threadIdx.x, blk = blockIdx.x;
  const int e0 = blk * EPB, e1 = min(NE, e0 + EPB);
  for (int e = e0 + t; e < e1; e += 256) {
    const int s = src[e], d = dst[e];
    if (idmap[d]) flag[s] = 1;
    if (idmap[s]) flag[d] = 1;
  }
}

// ---- mega: barrier-free encoder (blocks <EB2) + filtered hist + compact -----
__launch_bounds__(256)
__global__ void k_mega(const float* __restrict__ T, const ushort* __restrict__ Wt,
                       const float* __restrict__ bias,
                       const unsigned char* __restrict__ flag,
                       float* __restrict__ x, ushort* __restrict__ xb,
                       const int* __restrict__ src, const int* __restrict__ dst,
                       int* __restrict__ cm_f, int* __restrict__ cm_r,
                       int* __restrict__ frows, int* __restrict__ nf) {
  __shared__ int hf[NBUCK], hr[NBUCK];   // 3128 B (hist role only)
  const int bb = blockIdx.x;
  const int tid = threadIdx.x;
  if (bb < EB2) {
    // ====== encoder: A fragments direct from global, zero LDS / barriers =====
    const int row0 = bb * 128;
    const int wave = tid >> 6, lane = tid & 63;
    const int quad = lane >> 4, lr = lane & 15;
    const int rA = min(row0 + wave * 32 + lr, NN - 1);
    const int rB = min(row0 + wave * 32 + 16 + lr, NN - 1);
    const float* tpA = T + (size_t)rA * TXT + quad * 8;
    const float* tpB = T + (size_t)rB * TXT + quad * 8;
    const ushort* pw = Wt + lane * 8;

    float4 a0 = *(const float4*)(tpA);
    float4 a1 = *(const float4*)(tpA + 4);
    float4 b0 = *(const float4*)(tpB);
    float4 b1 = *(const float4*)(tpB + 4);
    float4v acc[2][4] = {};
    #pragma unroll
    for (int ch = 0; ch < 12; ++ch) {
      const short8 af0 = pack8(a0, a1);
      const short8 af1 = pack8(b0, b1);
      if (ch < 11) {                       // 1-deep prefetch of next chunk
        const float* qa = tpA + (ch + 1) * 32;
        const float* qb = tpB + (ch + 1) * 32;
        a0 = *(const float4*)(qa); a1 = *(const float4*)(qa + 4);
        b0 = *(const float4*)(qb); b1 = *(const float4*)(qb + 4);
      }
      #pragma unroll
      for (int nt = 0; nt < 4; ++nt) {
        const short8 bfrag = *(const short8*)(pw + (size_t)(ch * 4 + nt) * 512);
        acc[0][nt] = __builtin_amdgcn_mfma_f32_16x16x32_bf16(af0, bfrag, acc[0][nt], 0, 0, 0);
        acc[1][nt] = __builtin_amdgcn_mfma_f32_16x16x32_bf16(af1, bfrag, acc[1][nt], 0, 0, 0);
      }
    }
    #pragma unroll
    for (int nt = 0; nt < 4; ++nt) {
      const int col = nt * 16 + lr;
      const float bcol = bias[col];
      #pragma unroll
      for (int mt = 0; mt < 2; ++mt) {
        #pragma unroll
        for (int r = 0; r < 4; ++r) {
          const int row = row0 + wave * 32 + mt * 16 + quad * 4 + r;
          if (row < NN) {
            const float v = acc[mt][nt][r] + bcol;
            const size_t idx = (size_t)row * 64 + col;
            xb[idx] = f2bf(v);
            if (flag[row]) x[idx] = v;   // x f32 only read at frontier rows
          }
        }
      }
    }
  } else if (bb < EB2 + SBLK) {
    // ================= filtered per-(block,bucket) histogram =================
    const int blk = bb - EB2;
    for (int i = tid; i < NBUCK; i += 256) { hf[i] = 0; hr[i] = 0; }
    __syncthreads();
    const int e0 = blk * EPB, e1 = min(NE, e0 + EPB);
    for (int e = e0 + tid; e < e1; e += 256) {
      const int s = src[e], d = dst[e];
      if (flag[d]) atomicAdd(&hf[d >> 8], 1);
      if (flag[s]) atomicAdd(&hr[s >> 8], 1);
    }
    __syncthreads();
    for (int i = tid; i < NBUCK; i += 256) {
      cm_f[i * SBLK + blk] = hf[i];
      cm_r[i * SBLK + blk] = hr[i];
    }
  } else {
    // ================= compact flagged rows into frows =======================
    const int i = (bb - EB2 - SBLK) * 256 + tid;
    if (i < NN && flag[i]) frows[atomicAdd(nf, 1)] = i;
  }
}

// ---- per-bucket exclusive scan over the 256 block-counts (shuffle scan) -----
__global__ void k_scan1(int* __restrict__ cm_f, int* __restrict__ cm_r,
                        int* __restrict__ btot) {
  __shared__ int lds8[8];
  const int t = threadIdx.x;
  const int b = blockIdx.x;
  int* cm = (b < NBUCK) ? cm_f : cm_r;
  const int bucket = (b < NBUCK) ? b : b - NBUCK;
  int* row = cm + bucket * SBLK;
  const int v = row[t];
  const int incl = scan_incl(v, lds8);
  row[t] = incl - v;
  if (t == 255) btot[b] = incl;
}

// ---- exclusive scan of bucket totals -> bucket bases (shuffle scan) ---------
__global__ void k_scan2(const int* __restrict__ btot,
                        int* __restrict__ bbase_f, int* __restrict__ bbase_r) {
  __shared__ int lds8[8];
  const int t = threadIdx.x;   // 512 threads
  int h = (t < NBUCK) ? btot[t] : 0;
  int incl = scan_incl(h, lds8);
  if (t < NBUCK) bbase_f[t] = incl - h;
  h = (t < NBUCK) ? btot[NBUCK + t] : 0;
  incl = scan_incl(h, lds8);
  if (t < NBUCK) bbase_r[t] = incl - h;
}

// ---- scatter (filtered) with LDS cursors only -------------------------------
__global__ void k_scatter2(const int* __restrict__ src, const int* __restrict__ dst,
                           const float* __restrict__ w,
                           const unsigned char* __restrict__ flag,
                           const int* __restrict__ cm_f, const int* __restrict__ cm_r,
                           const int* __restrict__ bbase_f, const int* __restrict__ bbase_r,
                           int2* __restrict__ stg_f, int2* __restrict__ stg_r) {
  __shared__ int cur_f[NBUCK], cur_r[NBUCK];
  const int t = threadIdx.x, blk = blockIdx.x;
  for (int i = t; i < NBUCK; i += 256) {
    cur_f[i] = bbase_f[i] + cm_f[i * SBLK + blk];
    cur_r[i] = bbase_r[i] + cm_r[i * SBLK + blk];
  }
  __syncthreads();
  const int e0 = blk * EPB, e1 = min(NE, e0 + EPB);
  for (int e = e0 + t; e < e1; e += 256) {
    const int s = src[e], d = dst[e];
    const int wb = __float_as_int(w[e]);
    if (flag[d]) {
      const int p = atomicAdd(&cur_f[d >> 8], 1);
      stg_f[p] = make_int2(((d & 255) << 24) | s, wb);
    }
    if (flag[s]) {
      const int q = atomicAdd(&cur_r[s >> 8], 1);
      stg_r[q] = make_int2(((s & 255) << 24) | d, wb);
    }
  }
}

// ---- per-bucket CSR finalize + degree-sorted flagged-row permutation --------
__global__ void p_build(const unsigned char* __restrict__ flag,
                        const int2* __restrict__ stgf, const int* __restrict__ btotf,
                        const int* __restrict__ bbasef,
                        int* __restrict__ startf, int* __restrict__ cntf,
                        int2* __restrict__ cvf, int* __restrict__ permf,
                        const int2* __restrict__ stgr, const int* __restrict__ btotr,
                        const int* __restrict__ bbaser,
                        int* __restrict__ startr, int* __restrict__ cntr,
                        int2* __restrict__ cvr, int* __restrict__ permr) {
  int b = blockIdx.x;
  const int2* stg; const int* bcnt; const int* bbase;
  int* start; int* cnt; int2* cv; int* perm;
  if (b < NBUCK) { stg = stgf; bcnt = btotf; bbase = bbasef; start = startf; cnt = cntf; cv = cvf; perm = permf; }
  else { b -= NBUCK; stg = stgr; bcnt = btotr; bbase = bbaser; start = startr; cnt = cntr; cv = cvr; perm = permr; }
  const int base = bbase[b];
  const int n = bcnt[b];
  const int t = threadIdx.x;
  __shared__ int hist[256], cur[256], dh[256], dc[256], lds8[8];
  hist[t] = 0;
  perm[b * 256 + t] = -1;
  __syncthreads();
  for (int i = t; i < n; i += 256) {
    const unsigned pk = (unsigned)stg[base + i].x;
    atomicAdd(&hist[pk >> 24], 1);
  }
  __syncthreads();
  const int h = hist[t];
  const int excl = scan_incl(h, lds8) - h;
  const int node = (b << 8) + t;
  const bool valid = (node < NN) && flag[node];
  if (valid) { start[node] = base + excl; cnt[node] = h; }
  cur[t] = excl;
  // degree counting-sort over flagged rows only
  dh[t] = 0; __syncthreads();
  const int dcap = min(h, 255);
  if (valid) atomicAdd(&dh[dcap], 1);
  __syncthreads();
  const int dv = dh[t];
  dc[t] = scan_incl(dv, lds8) - dv;
  __syncthreads();
  if (valid) {
    const int pos = atomicAdd(&dc[dcap], 1);
    perm[b * 256 + pos] = node;
  }
  __syncthreads();
  for (int i = t; i < n; i += 256) {
    const int2 en = stg[base + i];
    const unsigned d8 = ((unsigned)en.x) >> 24;
    const int pos = atomicAdd(&cur[d8], 1);
    cv[base + pos] = make_int2(en.x & 0xFFFFFF, en.y);
  }
}

// ---- gather: degree-matched flagged rows, 16 lanes/row, 8B loads ------------
__global__ void k_gather3(const ushort* __restrict__ xb,
                          const int* __restrict__ permf, const int* __restrict__ startf,
                          const int* __restrict__ cntf, const int2* __restrict__ cvf,
                          ushort* __restrict__ nbf,
                          const int* __restrict__ permr, const int* __restrict__ startr,
                          const int* __restrict__ cntr, const int2* __restrict__ cvr,
                          ushort* __restrict__ nbr) {
  const int BPD = (NBUCK * 256) / 16;   // 6256 blocks per direction
  int b = blockIdx.x;
  const int *perm, *start, *cnt; const int2* cv; ushort* outp;
  if (b < BPD) { perm = permf; start = startf; cnt = cntf; cv = cvf; outp = nbf; }
  else { b -= BPD; perm = permr; start = startr; cnt = cntr; cv = cvr; outp = nbr; }
  const int lane = threadIdx.x & 63;
  const int wave = threadIdx.x >> 6;
  const int slot = b * 16 + wave * 4 + (lane >> 4);
  const int fl = (lane & 15) * 4;       // 16 lanes x 8 B = 128 B row
  const int row = perm[slot];
  if (row < 0) return;                  // perm holds only flagged rows
  const int s = start[row], c = cnt[row];
  const int e = s + c;
  float a0 = 0.f, a1 = 0.f, a2 = 0.f, a3 = 0.f;
  int j = s;
  for (; j + 4 <= e; j += 4) {
    int2 e0 = cv[j], e1 = cv[j + 1], e2 = cv[j + 2], e3 = cv[j + 3];
    uint2 v0 = *(const uint2*)(xb + (size_t)e0.x * 64 + fl);
    uint2 v1 = *(const uint2*)(xb + (size_t)e1.x * 64 + fl);
    uint2 v2 = *(const uint2*)(xb + (size_t)e2.x * 64 + fl);
    uint2 v3 = *(const uint2*)(xb + (size_t)e3.x * 64 + fl);
    float w0 = __int_as_float(e0.y), w1 = __int_as_float(e1.y);
    float w2 = __int_as_float(e2.y), w3 = __int_as_float(e3.y);
    a0 += w0 * bf2f((ushort)v0.x); a1 += w0 * bf2f((ushort)(v0.x >> 16));
    a2 += w0 * bf2f((ushort)v0.y); a3 += w0 * bf2f((ushort)(v0.y >> 16));
    a0 += w1 * bf2f((ushort)v1.x); a1 += w1 * bf2f((ushort)(v1.x >> 16));
    a2 += w1 * bf2f((ushort)v1.y); a3 += w1 * bf2f((ushort)(v1.y >> 16));
    a0 += w2 * bf2f((ushort)v2.x); a1 += w2 * bf2f((ushort)(v2.x >> 16));
    a2 += w2 * bf2f((ushort)v2.y); a3 += w2 * bf2f((ushort)(v2.y >> 16));
    a0 += w3 * bf2f((ushort)v3.x); a1 += w3 * bf2f((ushort)(v3.x >> 16));
    a2 += w3 * bf2f((ushort)v3.y); a3 += w3 * bf2f((ushort)(v3.y >> 16));
  }
  for (; j < e; ++j) {
    int2 ee = cv[j];
    uint2 v = *(const uint2*)(xb + (size_t)ee.x * 64 + fl);
    float ww = __int_as_float(ee.y);
    a0 += ww * bf2f((ushort)v.x); a1 += ww * bf2f((ushort)(v.x >> 16));
    a2 += ww * bf2f((ushort)v.y); a3 += ww * bf2f((ushort)(v.y >> 16));
  }
  const float inv = (c > 0) ? 1.0f / (float)c : 0.f;   // DGL mean
  uint2 pv;
  pv.x = (uint)f2bf(a0 * inv) | ((uint)f2bf(a1 * inv) << 16);
  pv.y = (uint)f2bf(a2 * inv) | ((uint)f2bf(a3 * inv) << 16);
  *(uint2*)(outp + (size_t)row * 64 + fl) = pv;
}

// ---- batch gather (layer 2): 1024 rows x 2 dirs, output indexed by batch ----
__global__ void k_bgather(const ushort* __restrict__ xb, const int* __restrict__ ids,
                          const int* __restrict__ startf, const int* __restrict__ cntf,
                          const int2* __restrict__ cvf, ushort* __restrict__ nbf,
                          const int* __restrict__ startr, const int* __restrict__ cntr,
                          const int2* __restrict__ cvr, ushort* __restrict__ nbr) {
  const int lane = threadIdx.x & 63;
  const int wave = threadIdx.x >> 6;
  const int fl = (lane & 15) * 4;
  const int t = blockIdx.x * 16 + wave * 4 + (lane >> 4);   // 0..2047
  const int rev = (t >= BATCH);
  const int b = rev ? t - BATCH : t;
  const int row = ids[b];
  const int* start = rev ? startr : startf;
  const int* cnt   = rev ? cntr   : cntf;
  const int2* cv   = rev ? cvr    : cvf;
  ushort* outp     = rev ? nbr    : nbf;
  const int s = start[row], c = cnt[row];
  const int e = s + c;
  float a0 = 0.f, a1 = 0.f, a2 = 0.f, a3 = 0.f;
  int j = s;
  for (; j + 4 <= e; j += 4) {
    int2 e0 = cv[j], e1 = cv[j + 1], e2 = cv[j + 2], e3 = cv[j + 3];
    uint2 v0 = *(const uint2*)(xb + (size_t)e0.x * 64 + fl);
    uint2 v1 = *(const uint2*)(xb + (size_t)e1.x * 64 + fl);
    uint2 v2 = *(const uint2*)(xb + (size_t)e2.x * 64 + fl);
    uint2 v3 = *(const uint2*)(xb + (size_t)e3.x * 64 + fl);
    float w0 = __int_as_float(e0.y), w1 = __int_as_float(e1.y);
    float w2 = __int_as_float(e2.y), w3 = __int_as_float(e3.y);
    a0 += w0 * bf2f((ushort)v0.x); a1 += w0 * bf2f((ushort)(v0.x >> 16));
    a2 += w0 * bf2f((ushort)v0.y); a3 += w0 * bf2f((ushort)(v0.y >> 16));
    a0 += w1 * bf2f((ushort)v1.x); a1 += w1 * bf2f((ushort)(v1.x >> 16));
    a2 += w1 * bf2f((ushort)v1.y); a3 += w1 * bf2f((ushort)(v1.y >> 16));
    a0 += w2 * bf2f((ushort)v2.x); a1 += w2 * bf2f((ushort)(v2.x >> 16));
    a2 += w2 * bf2f((ushort)v2.y); a3 += w2 * bf2f((ushort)(v2.y >> 16));
    a0 += w3 * bf2f((ushort)v3.x); a1 += w3 * bf2f((ushort)(v3.x >> 16));
    a2 += w3 * bf2f((ushort)v3.y); a3 += w3 * bf2f((ushort)(v3.y >> 16));
  }
  for (; j < e; ++j) {
    int2 ee = cv[j];
    uint2 v = *(const uint2*)(xb + (size_t)ee.x * 64 + fl);
    float ww = __int_as_float(ee.y);
    a0 += ww * bf2f((ushort)v.x); a1 += ww * bf2f((ushort)(v.x >> 16));
    a2 += ww * bf2f((ushort)v.y); a3 += ww * bf2f((ushort)(v.y >> 16));
  }
  const float inv = (c > 0) ? 1.0f / (float)c : 0.f;
  uint2 pv;
  pv.x = (uint)f2bf(a0 * inv) | ((uint)f2bf(a1 * inv) << 16);
  pv.y = (uint)f2bf(a2 * inv) | ((uint)f2bf(a3 * inv) << 16);
  *(uint2*)(outp + (size_t)b * 64 + fl) = pv;
}

// ---- layer 0 combine, frontier rows only (indirect via frows) ---------------
__launch_bounds__(256)
__global__ void k_layerf(const int* __restrict__ frows, const int* __restrict__ nfp,
                         const ushort* __restrict__ xbin,
                         const ushort* __restrict__ nbf, const ushort* __restrict__ nbr,
                         const float* __restrict__ Wsf, const float* __restrict__ Wnf,
                         const float* __restrict__ bfv,
                         const float* __restrict__ Wsr, const float* __restrict__ Wnr,
                         const float* __restrict__ brv,
                         float* __restrict__ x, ushort* __restrict__ xb) {
  const int nfv = *nfp;
  const int row0 = blockIdx.x * 128;
  if (row0 >= nfv) return;              // block-uniform early exit
  __shared__ short B4[4 * 64 * LDK2];   // 36 KB
  __shared__ short As[128 * LDK2];      // 18 KB
  const int tid = threadIdx.x;
  const int wave = tid >> 6, lane = tid & 63;
  const int quad = lane >> 4, lr = lane & 15;

  {
    #pragma unroll
    for (int j = 0; j < 16; ++j) {
      int idx = j * 256 + tid;
      int k = idx >> 6, n = idx & 63;
      B4[0 * 64 * LDK2 + n * LDK2 + k] = (short)f2bf(Wsf[idx]);
      B4[1 * 64 * LDK2 + n * LDK2 + k] = (short)f2bf(Wsr[idx]);
      B4[2 * 64 * LDK2 + n * LDK2 + k] = (short)f2bf(Wnf[idx]);
      B4[3 * 64 * LDK2 + n * LDK2 + k] = (short)f2bf(Wnr[idx]);
    }
  }
  const int srow = tid >> 1, half = (tid & 1) * 32;
  const int slot = row0 + srow;
  const int grow = frows[(slot < nfv) ? slot : 0];   // dup rows: loads only
  {
    const uint4* s = (const uint4*)(xbin + (size_t)grow * 64 + half);
    uint4* d = (uint4*)&As[srow * LDK2 + half];
    d[0] = s[0]; d[1] = s[1]; d[2] = s[2]; d[3] = s[3];
  }
  const uint4* pf = (const uint4*)(nbf + (size_t)grow * 64 + half);
  uint4 p0 = pf[0], p1 = pf[1], p2 = pf[2], p3 = pf[3];
  __syncthreads();

  float4v accf[2][4] = {}, accr[2][4] = {};
  #pragma unroll
  for (int kk = 0; kk < 64; kk += 32) {
    short8 a0 = *(const short8*)&As[(wave * 32 + lr) * LDK2 + kk + quad * 8];
    short8 a1 = *(const short8*)&As[(wave * 32 + 16 + lr) * LDK2 + kk + quad * 8];
    #pragma unroll
    for (int nt = 0; nt < 4; ++nt) {
      short8 bs = *(const short8*)&B4[0 * 64 * LDK2 + (nt * 16 + lr) * LDK2 + kk + quad * 8];
      accf[0][nt] = __builtin_amdgcn_mfma_f32_16x16x32_bf16(a0, bs, accf[0][nt], 0, 0, 0);
      accf[1][nt] = __builtin_amdgcn_mfma_f32_16x16x32_bf16(a1, bs, accf[1][nt], 0, 0, 0);
      short8 bq = *(const short8*)&B4[1 * 64 * LDK2 + (nt * 16 + lr) * LDK2 + kk + quad * 8];
      accr[0][nt] = __builtin_amdgcn_mfma_f32_16x16x32_bf16(a0, bq, accr[0][nt], 0, 0, 0);
      accr[1][nt] = __builtin_amdgcn_mfma_f32_16x16x32_bf16(a1, bq, accr[1][nt], 0, 0, 0);
    }
  }
  __syncthreads();
  { uint4* d = (uint4*)&As[srow * LDK2 + half]; d[0] = p0; d[1] = p1; d[2] = p2; d[3] = p3; }
  {
    const uint4* pr = (const uint4*)(nbr + (size_t)grow * 64 + half);
    p0 = pr[0]; p1 = pr[1]; p2 = pr[2]; p3 = pr[3];
  }
  __syncthreads();
  #pragma unroll
  for (int kk = 0; kk < 64; kk += 32) {
    short8 a0 = *(const short8*)&As[(wave * 32 + lr) * LDK2 + kk + quad * 8];
    short8 a1 = *(const short8*)&As[(wave * 32 + 16 + lr) * LDK2 + kk + quad * 8];
    #pragma unroll
    for (int nt = 0; nt < 4; ++nt) {
      short8 bs = *(const short8*)&B4[2 * 64 * LDK2 + (nt * 16 + lr) * LDK2 + kk + quad * 8];
      accf[0][nt] = __builtin_amdgcn_mfma_f32_16x16x32_bf16(a0, bs, accf[0][nt], 0, 0, 0);
      accf[1][nt] = __builtin_amdgcn_mfma_f32_16x16x32_bf16(a1, bs, accf[1][nt], 0, 0, 0);
    }
  }
  __syncthreads();
  { uint4* d = (uint4*)&As[srow * LDK2 + half]; d[0] = p0; d[1] = p1; d[2] = p2; d[3] = p3; }
  __syncthreads();
  #pragma unroll
  for (int kk = 0; kk < 64; kk += 32) {
    short8 a0 = *(const short8*)&As[(wave * 32 + lr) * LDK2 + kk + quad * 8];
    short8 a1 = *(const short8*)&As[(wave * 32 + 16 + lr) * LDK2 + kk + quad * 8];
    #pragma unroll
    for (int nt = 0; nt < 4; ++nt) {
      short8 bs = *(const short8*)&B4[3 * 64 * LDK2 + (nt * 16 + lr) * LDK2 + kk + quad * 8];
      accr[0][nt] = __builtin_amdgcn_mfma_f32_16x16x32_bf16(a0, bs, accr[0][nt], 0, 0, 0);
      accr[1][nt] = __builtin_amdgcn_mfma_f32_16x16x32_bf16(a1, bs, accr[1][nt], 0, 0, 0);
    }
  }
  #pragma unroll
  for (int nt = 0; nt < 4; ++nt) {
    const int col = nt * 16 + lr;
    const float bf_c = bfv[col], br_c = brv[col];
    #pragma unroll
    for (int mt = 0; mt < 2; ++mt) {
      #pragma unroll
      for (int r = 0; r < 4; ++r) {
        const int rl = wave * 32 + mt * 16 + quad * 4 + r;
        const int slotE = row0 + rl;
        if (slotE < nfv) {
          const int node = frows[slotE];
          const size_t idx = (size_t)node * 64 + col;
          const float v = x[idx] + fmaxf(accf[mt][nt][r] + bf_c, 0.f)
                                 + fmaxf(accr[mt][nt][r] + br_c, 0.f);
          x[idx] = v;
          xb[idx] = f2bf(v);
        }
      }
    }
  }
}

// ---- layer 2 on the 1024 batch rows only, fused with L2 normalize -----------
__launch_bounds__(256)
__global__ void k_blayer(const ushort* __restrict__ xbin, const float* __restrict__ x,
                         const int* __restrict__ ids,
                         const ushort* __restrict__ nbf, const ushort* __restrict__ nbr,
                         const float* __restrict__ Wsf, const float* __restrict__ Wnf,
                         const float* __restrict__ bfv,
                         const float* __restrict__ Wsr, const float* __restrict__ Wnr,
                         const float* __restrict__ brv,
                         float* __restrict__ out) {
  __shared__ short B4[4 * 64 * LDK2];   // 36 KB
  __shared__ short As[128 * LDK2];      // 18 KB
  const int tid = threadIdx.x;
  const int b0 = blockIdx.x * 128;      // 8 blocks x 128 batch rows
  const int wave = tid >> 6, lane = tid & 63;
  const int quad = lane >> 4, lr = lane & 15;

  #pragma unroll
  for (int j = 0; j < 16; ++j) {
    int idx = j * 256 + tid;
    int k = idx >> 6, n = idx & 63;
    B4[0 * 64 * LDK2 + n * LDK2 + k] = (short)f2bf(Wsf[idx]);
    B4[1 * 64 * LDK2 + n * LDK2 + k] = (short)f2bf(Wsr[idx]);
    B4[2 * 64 * LDK2 + n * LDK2 + k] = (short)f2bf(Wnf[idx]);
    B4[3 * 64 * LDK2 + n * LDK2 + k] = (short)f2bf(Wnr[idx]);
  }
  const int srow = tid >> 1, half = (tid & 1) * 32;
  const int node0 = ids[b0 + srow];
  {
    const uint4* s = (const uint4*)(xbin + (size_t)node0 * 64 + half);
    uint4* d = (uint4*)&As[srow * LDK2 + half];
    d[0] = s[0]; d[1] = s[1]; d[2] = s[2]; d[3] = s[3];
  }
  __syncthreads();

  float4v accf[2][4] = {}, accr[2][4] = {};
  #pragma unroll
  for (int kk = 0; kk < 64; kk += 32) {
    short8 a0 = *(const short8*)&As[(wave * 32 + lr) * LDK2 + kk + quad * 8];
    short8 a1 = *(const short8*)&As[(wave * 32 + 16 + lr) * LDK2 + kk + quad * 8];
    #pragma unroll
    for (int nt = 0; nt < 4; ++nt) {
      short8 bs = *(const short8*)&B4[0 * 64 * LDK2 + (nt * 16 + lr) * LDK2 + kk + quad * 8];
      accf[0][nt] = __builtin_amdgcn_mfma_f32_16x16x32_bf16(a0, bs, accf[0][nt], 0, 0, 0);
      accf[1][nt] = __builtin_amdgcn_mfma_f32_16x16x32_bf16(a1, bs, accf[1][nt], 0, 0, 0);
      short8 bq = *(const short8*)&B4[1 * 64 * LDK2 + (nt * 16 + lr) * LDK2 + kk + quad * 8];
      accr[0][nt] = __builtin_amdgcn_mfma_f32_16x16x32_bf16(a0, bq, accr[0][nt], 0, 0, 0);
      accr[1][nt] = __builtin_amdgcn_mfma_f32_16x16x32_bf16(a1, bq, accr[1][nt], 0, 0, 0);
    }
  }
  __syncthreads();
  {
    const uint4* s = (const uint4*)(nbf + (size_t)(b0 + srow) * 64 + half);
    uint4* d = (uint4*)&As[srow * LDK2 + half];
    d[0] = s[0]; d[1] = s[1]; d[2] = s[2]; d[3] = s[3];
  }
  __syncthreads();
  #pragma unroll
  for (int kk = 0; kk < 64; kk += 32) {
    short8 a0 = *(const short8*)&As[(wave * 32 + lr) * LDK2 + kk + quad * 8];
    short8 a1 = *(const short8*)&As[(wave * 32 + 16 + lr) * LDK2 + kk + quad * 8];
    #pragma unroll
    for (int nt = 0; nt < 4; ++nt) {
      short8 bs = *(const short8*)&B4[2 * 64 * LDK2 + (nt * 16 + lr) * LDK2 + kk + quad * 8];
      accf[0][nt] = __builtin_amdgcn_mfma_f32_16x16x32_bf16(a0, bs, accf[0][nt], 0, 0, 0);
      accf[1][nt] = __builtin_amdgcn_mfma_f32_16x16x32_bf16(a1, bs, accf[1][nt], 0, 0, 0);
    }
  }
  __syncthreads();
  {
    const uint4* s = (const uint4*)(nbr + (size_t)(b0 + srow) * 64 + half);
    uint4* d = (uint4*)&As[srow * LDK2 + half];
    d[0] = s[0]; d[1] = s[1]; d[2] = s[2]; d[3] = s[3];
  }
  __syncthreads();
  #pragma unroll
  for (int kk = 0; kk < 64; kk += 32) {
    short8 a0 = *(const short8*)&As[(wave * 32 + lr) * LDK2 + kk + quad * 8];
    short8 a1 = *(const short8*)&As[(wave * 32 + 16 + lr) * LDK2 + kk + quad * 8];
    #pragma unroll
    for (int nt = 0; nt < 4; ++nt) {
      short8 bs = *(const short8*)&B4[3 * 64 * LDK2 + (nt * 16 + lr) * LDK2 + kk + quad * 8];
      accr[0][nt] = __builtin_amdgcn_mfma_f32_16x16x32_bf16(a0, bs, accr[0][nt], 0, 0, 0);
      accr[1][nt] = __builtin_amdgcn_mfma_f32_16x16x32_bf16(a1, bs, accr[1][nt], 0, 0, 0);
    }
  }
  float vv[2][4][4];
  #pragma unroll
  for (int nt = 0; nt < 4; ++nt) {
    const int col = nt * 16 + lr;
    const float bf_c = bfv[col], br_c = brv[col];
    #pragma unroll
    for (int mt = 0; mt < 2; ++mt) {
      #pragma unroll
      for (int r = 0; r < 4; ++r) {
        const int rl = wave * 32 + mt * 16 + quad * 4 + r;
        const int node = ids[b0 + rl];
        vv[mt][nt][r] = x[(size_t)node * 64 + col]
                      + fmaxf(accf[mt][nt][r] + bf_c, 0.f)
                      + fmaxf(accr[mt][nt][r] + br_c, 0.f);
      }
    }
  }
  #pragma unroll
  for (int mt = 0; mt < 2; ++mt) {
    #pragma unroll
    for (int r = 0; r < 4; ++r) {
      float s = 0.f;
      #pragma unroll
      for (int nt = 0; nt < 4; ++nt) s += vv[mt][nt][r] * vv[mt][nt][r];
      s += __shfl_xor(s, 1); s += __shfl_xor(s, 2);
      s += __shfl_xor(s, 4); s += __shfl_xor(s, 8);   // reduce over 16 lr lanes
      const int rl = wave * 32 + mt * 16 + quad * 4 + r;
      const float inv = 1.f / sqrtf(s);
      #pragma unroll
      for (int nt = 0; nt < 4; ++nt)
        out[(size_t)(b0 + rl) * 64 + nt * 16 + lr] = vv[mt][nt][r] * inv;
    }
  }
}

extern "C" void kernel_launch(void* const* d_in, const int* in_sizes, int n_in,
                              void* d_out, int out_size, void* d_ws, size_t ws_size,
                              hipStream_t stream) {
  const float* text = (const float*)d_in[0];
  const float* wts  = (const float*)d_in[1];
  const float* Wenc = (const float*)d_in[2];
  const float* benc = (const float*)d_in[3];
  const float* Wsf  = (const float*)d_in[4];
  const float* Wnf  = (const float*)d_in[5];
  const float* bf   = (const float*)d_in[6];
  const float* Wsr  = (const float*)d_in[7];
  const float* Wnr  = (const float*)d_in[8];
  const float* br   = (const float*)d_in[9];
  const int*   src  = (const int*)d_in[10];
  const int*   dst  = (const int*)d_in[11];
  const int*   ids  = (const int*)d_in[12];
  float* out = (float*)d_out;

  char* ws = (char*)d_ws;
  size_t o = 0;
  auto alloc = [&](size_t f32elems) {
    void* p = ws + o;
    o += f32elems * 4;
    o = (o + 255) & ~(size_t)255;
    return p;
  };
  float*  x   = (float*)alloc((size_t)NN * 64);
  ushort* xb  = (ushort*)alloc((size_t)NN * 32);  // bf16 mirror of x
  ushort* nbf = (ushort*)alloc((size_t)NN * 32);  // bf16 neigh fwd; aliased stage_f
  ushort* nbr = (ushort*)alloc((size_t)NN * 32);  // bf16 neigh rev; aliased stage_r
  ushort* Wt  = (ushort*)alloc(48 * 512 / 2);     // tiled bf16 W_enc (48 KB)
  int2*   cvf = (int2*)alloc((size_t)NE * 2);     // final CSR (col, weight)
  int2*   cvr = (int2*)alloc((size_t)NE * 2);
  int* cm_f    = (int*)alloc((size_t)NBUCK * SBLK);
  int* cm_r    = (int*)alloc((size_t)NBUCK * SBLK);
  int* btot    = (int*)alloc(2 * NBUCK);
  int* bbase_f = (int*)alloc(NBUCK);
  int* bbase_r = (int*)alloc(NBUCK);
  int* startf  = (int*)alloc(NN);
  int* cntf    = (int*)alloc(NN);
  int* startr  = (int*)alloc(NN);
  int* cntr    = (int*)alloc(NN);
  int* permf   = (int*)alloc((size_t)NBUCK * 256);  // degree-sorted flagged rows
  int* permr   = (int*)alloc((size_t)NBUCK * 256);
  unsigned char* idmap = (unsigned char*)alloc(NN / 4 + 64);  // batch-id bitmap
  unsigned char* flag  = (unsigned char*)alloc(NN / 4 + 64);  // frontier bitmap
  int* frows = (int*)alloc(NN);                     // compacted frontier rows
  int* nf    = (int*)alloc(64);                     // frontier count

  int2* stg_f = (int2*)nbf;   // staging dead before gathers write nbf
  int2* stg_r = (int2*)nbr;

  k_init<<<12 + 98, 256, 0, stream>>>(Wenc, Wt, idmap, flag, nf);
  k_seed<<<1, 1024, 0, stream>>>(ids, idmap, flag);
  k_fedges<<<SBLK, 256, 0, stream>>>(src, dst, idmap, flag);
  // barrier-free encoder (782) + filtered hist (256) + compaction (391)
  k_mega<<<EB2 + SBLK + 391, 256, 0, stream>>>(text, Wt, benc, flag, x, xb,
                                               src, dst, cm_f, cm_r, frows, nf);
  k_scan1<<<2 * NBUCK, 256, 0, stream>>>(cm_f, cm_r, btot);
  k_scan2<<<1, 512, 0, stream>>>(btot, bbase_f, bbase_r);
  k_scatter2<<<SBLK, 256, 0, stream>>>(src, dst, wts, flag, cm_f, cm_r,
                                       bbase_f, bbase_r, stg_f, stg_r);
  p_build<<<2 * NBUCK, 256, 0, stream>>>(flag,
                                         stg_f, btot, bbase_f, startf, cntf, cvf, permf,
                                         stg_r, btot + NBUCK, bbase_r, startr, cntr, cvr, permr);
  const int GB3 = 2 * ((NBUCK * 256) / 16);
  k_gather3<<<GB3, 256, 0, stream>>>(xb, permf, startf, cntf, cvf, nbf,
                                     permr, startr, cntr, cvr, nbr);
  k_layerf<<<EB2, 256, 0, stream>>>(frows, nf, xb, nbf, nbr,
                                    Wsf, Wnf, bf, Wsr, Wnr, br, x, xb);
  k_bgather<<<(2 * BATCH) / 16, 256, 0, stream>>>(xb, ids, startf, cntf, cvf, nbf,
                                                  startr, cntr, cvr, nbr);
  k_blayer<<<BATCH / 128, 256, 0, stream>>>(xb, x, ids, nbf, nbr,
                                            Wsf + HID * HID, Wnf + HID * HID, bf + HID,
                                            Wsr + HID * HID, Wnr + HID * HID, br + HID,
                                            out);
}